// Round 1
// baseline (68.013 us; speedup 1.0000x reference)
//
#include <hip/hip_runtime.h>
#include <hip/hip_bf16.h>

#define B_ 4
#define T_ 800
#define U_ 150
#define D_ 512
#define H_ 256
#define PADH 260   // 260 % 32 == 4 -> per-row stride breaks bank aliasing to 2-way (free)

static constexpr float ARG_SCALE = 2.8853900817779268f; // 2/ln(2): tanh(x)=1-2/(1+2^(c*x))
static constexpr float LOG2E_F   = 1.4426950408889634f;

extern "C" __device__ float __ocml_exp2_f32(float);

__device__ __forceinline__ float fast_exp2(float x) {
#if __has_builtin(__builtin_amdgcn_exp2f)
    return __builtin_amdgcn_exp2f(x);   // v_exp_f32
#else
    return __ocml_exp2_f32(x);
#endif
}
__device__ __forceinline__ float fast_rcp(float x) {
#if __has_builtin(__builtin_amdgcn_rcpf)
    return __builtin_amdgcn_rcpf(x);    // v_rcp_f32
#else
    return 1.0f / x;
#endif
}

// ---------------------------------------------------------------------------
// K1: projections. rows 0..3199 = enc (B*T), rows 0..599 = dec (B*U).
// out[row,h] = c * (bias[h] + sum_e in[row,e] * W[e,h])
// 8 rows per 256-thread block; thread = one h column.
// ---------------------------------------------------------------------------
__global__ __launch_bounds__(256) void proj_kernel(
    const float* __restrict__ enc, const float* __restrict__ dec,
    const float* __restrict__ W_enc, const float* __restrict__ b_enc,
    const float* __restrict__ W_dec, const float* __restrict__ b_dec,
    float* __restrict__ enc_p, float* __restrict__ dec_p)
{
    const int tid = threadIdx.x;
    const int blk = blockIdx.x;
    const float* in; const float* Wm; const float* bias; float* outp; int row0;
    if (blk < 400) { in = enc; Wm = W_enc; bias = b_enc; outp = enc_p; row0 = blk * 8; }
    else           { in = dec; Wm = W_dec; bias = b_dec; outp = dec_p; row0 = (blk - 400) * 8; }

    __shared__ float lds[8][D_];
    // stage 8 rows x 512 floats = 1024 float4 / 256 threads
    const float4* src = (const float4*)(in + (size_t)row0 * D_);
    float4* dst = (float4*)(&lds[0][0]);
    #pragma unroll
    for (int k = 0; k < 4; ++k) dst[tid + 256 * k] = src[tid + 256 * k];
    __syncthreads();

    const int h = tid;
    const float bh = bias[h];
    float acc[8];
    #pragma unroll
    for (int r = 0; r < 8; ++r) acc[r] = bh;

    for (int e4 = 0; e4 < D_ / 4; ++e4) {
        const float w0 = Wm[(4 * e4 + 0) * H_ + h];
        const float w1 = Wm[(4 * e4 + 1) * H_ + h];
        const float w2 = Wm[(4 * e4 + 2) * H_ + h];
        const float w3 = Wm[(4 * e4 + 3) * H_ + h];
        #pragma unroll
        for (int r = 0; r < 8; ++r) {
            float4 v = *(const float4*)&lds[r][4 * e4];   // broadcast read
            acc[r] = fmaf(v.w, w3, fmaf(v.z, w2, fmaf(v.y, w1, fmaf(v.x, w0, acc[r]))));
        }
    }
    #pragma unroll
    for (int r = 0; r < 8; ++r)
        outp[(size_t)(row0 + r) * H_ + h] = ARG_SCALE * acc[r];
}

// ---------------------------------------------------------------------------
// K2: scores. Block = 16 t x 16 u tile; thread (ty,tx) owns one (t,u) pair.
// acc = sum_h w[h] * rcp(1 + exp2(e'[t,h] + d'[u,h]))   (e',d' pre-scaled by c)
// True score = const(t) - 2*acc; constants cancel in the u-softmax.
// ---------------------------------------------------------------------------
__global__ __launch_bounds__(256) void score_kernel(
    const float* __restrict__ enc_p, const float* __restrict__ dec_p,
    const float* __restrict__ w_score, float* __restrict__ out)
{
    const int tid = threadIdx.x;
    const int ut = blockIdx.x, tt = blockIdx.y, b = blockIdx.z;

    __shared__ float eld[16][PADH];
    __shared__ float dld[16][PADH];
    __shared__ float wld[H_];

    if (tid < 64) ((float4*)wld)[tid] = ((const float4*)w_score)[tid];

    const int t0 = tt * 16, u0 = ut * 16;
    #pragma unroll
    for (int k = 0; k < 4; ++k) {
        int idx = tid + 256 * k;
        int row = idx >> 6;        // 0..15
        int f4  = idx & 63;        // 0..63
        float4 ev = ((const float4*)(enc_p + (size_t)(b * T_ + t0 + row) * H_))[f4];
        *(float4*)&eld[row][f4 * 4] = ev;
        int du = u0 + row; if (du > U_ - 1) du = U_ - 1;
        float4 dv = ((const float4*)(dec_p + (size_t)(b * U_ + du) * H_))[f4];
        *(float4*)&dld[row][f4 * 4] = dv;
    }
    __syncthreads();

    const int tx = tid & 15, ty = tid >> 4;
    const float* ep = &eld[ty][0];
    const float* dp = &dld[tx][0];

    float a0 = 0.f, a1 = 0.f, a2 = 0.f, a3 = 0.f;
    #pragma unroll 8
    for (int h4 = 0; h4 < H_ / 4; ++h4) {
        float4 e = *(const float4*)(ep + 4 * h4);
        float4 d = *(const float4*)(dp + 4 * h4);
        float4 w = *(const float4*)(wld + 4 * h4);
        float r0 = fast_rcp(1.f + fast_exp2(e.x + d.x));
        float r1 = fast_rcp(1.f + fast_exp2(e.y + d.y));
        float r2 = fast_rcp(1.f + fast_exp2(e.z + d.z));
        float r3 = fast_rcp(1.f + fast_exp2(e.w + d.w));
        a0 = fmaf(w.x, r0, a0);
        a1 = fmaf(w.y, r1, a1);
        a2 = fmaf(w.z, r2, a2);
        a3 = fmaf(w.w, r3, a3);
    }
    const float acc = (a0 + a1) + (a2 + a3);

    const int t = t0 + ty, u = u0 + tx;
    if (u < U_) out[(size_t)(b * T_ + t) * U_ + u] = acc;
}

// ---------------------------------------------------------------------------
// K3: in-place softmax over U=150 of z = -2*acc. One wave per row.
// ---------------------------------------------------------------------------
__global__ __launch_bounds__(256) void softmax_kernel(float* __restrict__ io)
{
    const int tid  = threadIdx.x;
    const int wave = tid >> 6, lane = tid & 63;
    const int row  = blockIdx.x * 4 + wave;       // 0..3199
    float* p = io + (size_t)row * U_;

    float s0 = p[lane];
    float s1 = p[lane + 64];
    const bool v2 = (lane + 128) < U_;
    float s2 = v2 ? p[lane + 128] : 0.f;

    float z0 = -2.f * s0, z1 = -2.f * s1;
    float z2 = v2 ? -2.f * s2 : -INFINITY;

    float m = fmaxf(fmaxf(z0, z1), z2);
    #pragma unroll
    for (int off = 32; off > 0; off >>= 1) m = fmaxf(m, __shfl_xor(m, off));

    float p0 = fast_exp2((z0 - m) * LOG2E_F);
    float p1 = fast_exp2((z1 - m) * LOG2E_F);
    float p2 = v2 ? fast_exp2((z2 - m) * LOG2E_F) : 0.f;

    float s = p0 + p1 + p2;
    #pragma unroll
    for (int off = 32; off > 0; off >>= 1) s += __shfl_xor(s, off);

    const float inv = 1.0f / s;   // IEEE divide for accuracy
    p[lane]       = p0 * inv;
    p[lane + 64]  = p1 * inv;
    if (v2) p[lane + 128] = p2 * inv;
}

// ---------------------------------------------------------------------------
extern "C" void kernel_launch(void* const* d_in, const int* in_sizes, int n_in,
                              void* d_out, int out_size, void* d_ws, size_t ws_size,
                              hipStream_t stream) {
    const float* enc     = (const float*)d_in[0];
    const float* dec     = (const float*)d_in[1];
    const float* W_enc   = (const float*)d_in[2];
    const float* b_enc   = (const float*)d_in[3];
    const float* W_dec   = (const float*)d_in[4];
    const float* b_dec   = (const float*)d_in[5];
    const float* w_score = (const float*)d_in[6];
    // d_in[7] = b_score: cancels in softmax, unused.

    float* enc_p = (float*)d_ws;                       // [B*T, H] scaled enc projection
    float* dec_p = enc_p + (size_t)B_ * T_ * H_;       // [B*U, H] scaled dec projection
    float* out   = (float*)d_out;

    proj_kernel<<<475, 256, 0, stream>>>(enc, dec, W_enc, b_enc, W_dec, b_dec, enc_p, dec_p);
    score_kernel<<<dim3(10, 50, 4), 256, 0, stream>>>(enc_p, dec_p, w_score, out);
    softmax_kernel<<<800, 256, 0, stream>>>(out);
}